// Round 4
// baseline (104.174 us; speedup 1.0000x reference)
//
#include <hip/hip_runtime.h>
#include <hip/hip_bf16.h>
#include <stdint.h>

#define BB   2
#define NN   2048
#define BN   (BB*NN)
#define KTOP 48
#define EIN  416
#define EF   128

typedef __attribute__((ext_vector_type(8))) short s8v;
typedef __attribute__((ext_vector_type(4))) float f32x4;
typedef __attribute__((ext_vector_type(4))) unsigned int u32x4;
typedef unsigned short u16;
typedef unsigned int u32;
typedef unsigned long long u64;

__device__ __constant__ int cPA[25] = {1,0,2,3,4,1,1,1,1,0,0,0,4,4,3,0,2,3,4,2,3,4,2,3,2};
__device__ __constant__ int cPB[25] = {1,0,2,3,4,0,2,3,4,2,3,4,2,3,2,1,1,1,1,0,0,0,4,4,3};

__device__ __forceinline__ u16 bf16u(float x) {
  __hip_bfloat16 h = __float2bfloat16(x);
  return *reinterpret_cast<u16*>(&h);
}
__device__ __forceinline__ u32 pack2(float lo, float hi) {
  return (u32)bf16u(lo) | ((u32)bf16u(hi) << 16);
}

// ---------------- prep: padded atoms [BN][5][4], Ca pack [BN][4], W_edge MFMA-tiled bf16 ----
__global__ __launch_bounds__(256) void prep_kernel(const float* __restrict__ X,
                                                   const float* __restrict__ W_edge,
                                                   float* __restrict__ atoms5p,
                                                   float* __restrict__ capack4,
                                                   u16* __restrict__ wtf) {
  int tid = blockIdx.x * 256 + threadIdx.x;
  if (tid < EIN * EF) {
    int k = tid >> 7, n = tid & 127;
    wtf[((size_t)(k >> 3)) * 1024 + n * 8 + (k & 7)] = bf16u(W_edge[tid]);
  } else if (tid < EIN * EF + BN) {
    int idx = tid - EIN * EF;
    const float* x = X + (size_t)idx * 12;
    float Nx = x[0], Ny = x[1], Nz = x[2];
    float Cax = x[3], Cay = x[4], Caz = x[5];
    float Cx = x[6], Cy = x[7], Cz = x[8];
    float Ox = x[9], Oy = x[10], Oz = x[11];
    float bx = Cax - Nx, by = Cay - Ny, bz = Caz - Nz;
    float cx = Cx - Cax, cy = Cy - Cay, cz = Cz - Caz;
    float ax = by * cz - bz * cy;
    float ay = bz * cx - bx * cz;
    float az = bx * cy - by * cx;
    float Cbx = -0.58273431f * ax + 0.56802827f * bx - 0.54067466f * cx + Cax;
    float Cby = -0.58273431f * ay + 0.56802827f * by - 0.54067466f * cy + Cay;
    float Cbz = -0.58273431f * az + 0.56802827f * bz - 0.54067466f * cz + Caz;
    f32x4* o = (f32x4*)(atoms5p + (size_t)idx * 20);
    o[0] = (f32x4){Nx, Ny, Nz, 0.f};
    o[1] = (f32x4){Cax, Cay, Caz, 0.f};
    o[2] = (f32x4){Cx, Cy, Cz, 0.f};
    o[3] = (f32x4){Ox, Oy, Oz, 0.f};
    o[4] = (f32x4){Cbx, Cby, Cbz, 0.f};
    *(f32x4*)(capack4 + (size_t)idx * 4) = (f32x4){Cax, Cay, Caz, 0.f};
  }
}

// exclusive block scan over 256 threads
__device__ __forceinline__ u32 blockExclScan(u32 v, u32* scanw, int t) {
  int lane = t & 63, w = t >> 6;
  u32 inc = v;
#pragma unroll
  for (int off = 1; off < 64; off <<= 1) {
    u32 o = __shfl_up(inc, off);
    if (lane >= off) inc += o;
  }
  if (lane == 63) scanw[w] = inc;
  __syncthreads();
  u32 base = 0;
  for (int ww = 0; ww < w; ++ww) base += scanw[ww];
  __syncthreads();
  return base + inc - v;
}

template<int NB, bool CHKPREF>
__device__ __forceinline__ void radix_round(u32* hist, u32* scanw, u32* selinfo, int t,
                                            const u32* kv, u32 pref, int prefShift,
                                            int binShift, u32 binMask, u32 r) {
  const int PB = NB / 256;
#pragma unroll
  for (int q = 0; q < PB / 4; ++q)
    *(u32x4*)&hist[t * PB + q * 4] = (u32x4){0, 0, 0, 0};
  __syncthreads();
#pragma unroll
  for (int s = 0; s < 8; ++s) {
    bool ok = (!CHKPREF) || ((kv[s] >> prefShift) == pref);
    if (ok) atomicAdd(&hist[(kv[s] >> binShift) & binMask], 1u);
  }
  __syncthreads();
  u32 loc[PB];
  u32 sum = 0;
#pragma unroll
  for (int q = 0; q < PB / 4; ++q) {
    u32x4 lv = *(u32x4*)&hist[t * PB + q * 4];
    loc[q * 4 + 0] = lv.x; loc[q * 4 + 1] = lv.y;
    loc[q * 4 + 2] = lv.z; loc[q * 4 + 3] = lv.w;
    sum += lv.x + lv.y + lv.z + lv.w;
  }
  int lane = t & 63, w = t >> 6;
  u32 inc = sum;
#pragma unroll
  for (int off = 1; off < 64; off <<= 1) {
    u32 o = __shfl_up(inc, off);
    if (lane >= off) inc += o;
  }
  if (lane == 63) scanw[w] = inc;
  __syncthreads();
  u32 base = 0;
  for (int ww = 0; ww < w; ++ww) base += scanw[ww];
  u32 c = base + inc - sum;
#pragma unroll
  for (int q = 0; q < PB; ++q) {
    u32 nc = c + loc[q];
    if (c < r && r <= nc) { selinfo[0] = (u32)(t * PB + q); selinfo[1] = r - c; }
    c = nc;
  }
  __syncthreads();
}

// ---------------- top-48 per row: exact radix select ----------------
__global__ __launch_bounds__(256) void topk_kernel(const float* __restrict__ capack4,
                                                   const float* __restrict__ mask,
                                                   float* __restrict__ dtop,
                                                   float* __restrict__ eidx_f) {
  __shared__ u32 hist[4096];
  __shared__ u32 scanw[4];
  __shared__ u32 selinfo[2];
  __shared__ float redf[4];
  __shared__ u64 win[64];

  int row = blockIdx.x;
  int b = row >> 11, i = row & (NN - 1);
  int t = threadIdx.x, lane = t & 63, w = t >> 6;
  const float* cab4 = capack4 + (size_t)b * NN * 4;
  const float* mrow = mask + (size_t)b * NN;
  f32x4 ci = *(const f32x4*)&cab4[(size_t)i * 4];
  float mi = mrow[i];
  f32x4 mk0 = *(const f32x4*)&mrow[t * 8];
  f32x4 mk1 = *(const f32x4*)&mrow[t * 8 + 4];

  float dvv[8], m2v[8];
  float lmax = 0.f;
#pragma unroll
  for (int s = 0; s < 8; ++s) {
    f32x4 cj = *(const f32x4*)&cab4[(size_t)(t * 8 + s) * 4];
    float dx = ci.x - cj.x, dy = ci.y - cj.y, dz = ci.z - cj.z;
    float d = sqrtf(dx * dx + dy * dy + dz * dz + 1e-6f);
    float mj = (s < 4) ? mk0[s] : mk1[s - 4];
    float m2 = mi * mj;
    float D = m2 * d;
    dvv[s] = D; m2v[s] = m2;
    lmax = fmaxf(lmax, D);
  }
#pragma unroll
  for (int off = 32; off >= 1; off >>= 1) lmax = fmaxf(lmax, __shfl_xor(lmax, off));
  if (lane == 0) redf[w] = lmax;
  __syncthreads();
  float rmax = fmaxf(fmaxf(redf[0], redf[1]), fmaxf(redf[2], redf[3]));

  u32 kv[8];
#pragma unroll
  for (int s = 0; s < 8; ++s)
    kv[s] = __float_as_uint(dvv[s] + (1.0f - m2v[s]) * rmax);

  u32 r = KTOP;
  radix_round<4096, false>(hist, scanw, selinfo, t, kv, 0, 0, 20, 0xFFFu, r);
  u32 sel1 = selinfo[0]; r = selinfo[1];
  radix_round<1024, true>(hist, scanw, selinfo, t, kv, sel1, 20, 10, 0x3FFu, r);
  u32 sel2 = selinfo[0]; r = selinfo[1];
  u32 pref12 = (sel1 << 10) | sel2;
  radix_round<1024, true>(hist, scanw, selinfo, t, kv, pref12, 10, 0, 0x3FFu, r);
  u32 sel3 = selinfo[0];
  u32 takeEq = selinfo[1];
  u32 T = (sel1 << 20) | (sel2 << 10) | sel3;

  u32 lcnt = 0, ecnt = 0;
#pragma unroll
  for (int s = 0; s < 8; ++s) { lcnt += (kv[s] < T); ecnt += (kv[s] == T); }
  u32 ebase = blockExclScan(ecnt, scanw, t);
  u32 taken = 0;
  if (ebase < takeEq) { u32 room = takeEq - ebase; taken = room < ecnt ? room : ecnt; }
  u32 wbase = blockExclScan(lcnt + taken, scanw, t);
  u32 slot = wbase, tleft = taken;
#pragma unroll
  for (int s = 0; s < 8; ++s) {
    u32 j = (u32)(t * 8 + s);
    if (kv[s] < T) {
      win[slot++] = ((u64)kv[s] << 32) | j;
    } else if (kv[s] == T && tleft) {
      win[slot++] = ((u64)kv[s] << 32) | j;
      tleft--;
    }
  }
  __syncthreads();

  if (w == 0) {
    u64 key = (lane < KTOP) ? win[lane] : ~0ull;
#pragma unroll
    for (int k = 2; k <= 64; k <<= 1) {
#pragma unroll
      for (int jj = k >> 1; jj >= 1; jj >>= 1) {
        u64 p = __shfl_xor(key, jj);
        bool lowerl = (lane & jj) == 0;
        bool asc = (lane & k) == 0;
        u64 mn = p < key ? p : key;
        u64 mx = p < key ? key : p;
        key = (lowerl == asc) ? mn : mx;
      }
    }
    if (lane < KTOP) {
      u32 j = (u32)(key & 0xffffffffu);
      eidx_f[row * KTOP + lane] = (float)j;
      dtop[row * KTOP + lane] = __uint_as_float((u32)(key >> 32));
    }
  }
}

// RBF 8-fragment: D -> 8 consecutive RBF values starting at mu0, packed bf16
__device__ __forceinline__ s8v rbf8(float D, float mu0) {
  float Dc = fminf(D, 40.0f);
  float t0 = (Dc - mu0) * 0.8f;
  float v0 = __expf(-t0 * t0);
  float g = __expf(fmaf(2.13333333f, t0, -1.13777778f));
  const float C = 0.10273985f;
  float v1 = v0 * g; g *= C;
  float v2 = v1 * g; g *= C;
  float v3 = v2 * g; g *= C;
  float v4 = v3 * g; g *= C;
  float v5 = v4 * g; g *= C;
  float v6 = v5 * g; g *= C;
  float v7 = v6 * g;
  union { u32x4 u; s8v s; } cv;
  cv.u = (u32x4){pack2(v0, v1), pack2(v2, v3), pack2(v4, v5), pack2(v6, v7)};
  return cv.s;
}

// ---------------- edge: distances in LDS, features fused into MFMA GEMM ----------------
__global__ __launch_bounds__(256, 4) void edge_kernel(const float* __restrict__ atoms5p,
                                                      const u16* __restrict__ wtf,
                                                      const float* __restrict__ eidx_f,
                                                      const float* __restrict__ dtop,
                                                      const int* __restrict__ Ridx,
                                                      const int* __restrict__ chains,
                                                      const float* __restrict__ Wpos,
                                                      const float* __restrict__ bpos,
                                                      const float* __restrict__ bedge,
                                                      float* __restrict__ Eout) {
  __shared__ float D_lds[KTOP][29];     // p=0: dtop, p=1..24: pair dists (29-pad: conflict-free)
  __shared__ u32 pos_lds[KTOP][8];      // positional cols 0..15 packed bf16
  __shared__ f32x4 aJ[KTOP][5];
  __shared__ f32x4 aI[5];
  __shared__ int jbuf[KTOP];

  int row = blockIdx.x;
  int b = row >> 11, i = row & (NN - 1);
  int t = threadIdx.x;
  const float* atomsB = atoms5p + (size_t)b * NN * 20;

  // phase 0: gather neighbor atoms, self atoms, dtop
  if (t < KTOP * 5) {
    int k = t / 5, a = t - k * 5;
    int j = (int)eidx_f[row * KTOP + k];
    aJ[k][a] = *(const f32x4*)&atomsB[(size_t)j * 20 + a * 4];
    if (a == 0) jbuf[k] = j;
  } else if (t < KTOP * 5 + 5) {
    int a = t - KTOP * 5;
    aI[a] = *(const f32x4*)&atomsB[(size_t)i * 20 + a * 4];
  }
  if (t < KTOP) D_lds[t][0] = dtop[row * KTOP + t];
  __syncthreads();

  // phase 1: 1152 pair distances + 48 positional rows
#pragma unroll
  for (int q = 0; q < 5; ++q) {
    int e = t + q * 256;
    if (e < 1152) {
      int k = e / 24;
      int p = e - k * 24 + 1;
      f32x4 I = aI[cPA[p]];
      f32x4 J = aJ[k][cPB[p]];
      float dx = I.x - J.x, dy = I.y - J.y, dz = I.z - J.z;
      D_lds[k][p] = __builtin_amdgcn_sqrtf(dx * dx + dy * dy + dz * dz + 1e-6f);
    } else if (e < 1200) {
      int k = e - 1152;
      int j = jbuf[k];
      int Ri = Ridx[b * NN + i], Rj = Ridx[b * NN + j];
      int same = (chains[b * NN + i] == chains[b * NN + j]);
      int off = Ri - Rj + 32;
      off = off < 0 ? 0 : (off > 64 ? 64 : off);
      int drow = same ? off : 65;
      const float* wr = Wpos + drow * 16;
      u32 pk[8];
#pragma unroll
      for (int h = 0; h < 4; ++h) {
        f32x4 wv = *(const f32x4*)&wr[h * 4];
        f32x4 bv = *(const f32x4*)&bpos[h * 4];
        pk[h * 2 + 0] = pack2(wv.x + bv.x, wv.y + bv.y);
        pk[h * 2 + 1] = pack2(wv.z + bv.z, wv.w + bv.w);
      }
      *(u32x4*)&pos_lds[k][0] = (u32x4){pk[0], pk[1], pk[2], pk[3]};
      *(u32x4*)&pos_lds[k][4] = (u32x4){pk[4], pk[5], pk[6], pk[7]};
    }
  }
  __syncthreads();

  // phase 2: GEMM with A-fragments generated in-register
  int w = t >> 6, lane = t & 63;
  int lr = lane & 15, lg = lane >> 4;
  int col0 = w * 32 + lr, col1 = col0 + 16;
  const float MU8 = 12.6666667f;  // 2 + 8*(20/15)
  f32x4 acc[3][2] = {};

  {  // kc = 0: cols 0..15 positional, 16..31 = RBF block p=0 (dtop)
    s8v bf0 = *reinterpret_cast<const s8v*>(&wtf[(size_t)lg * 1024 + col0 * 8]);
    s8v bf1 = *reinterpret_cast<const s8v*>(&wtf[(size_t)lg * 1024 + col1 * 8]);
#pragma unroll
    for (int mt = 0; mt < 3; ++mt) {
      int m = mt * 16 + lr;
      s8v af;
      if (lg < 2) {
        af = *reinterpret_cast<const s8v*>(&pos_lds[m][lg * 4]);
      } else {
        af = rbf8(D_lds[m][0], (lg == 2) ? 2.0f : MU8);
      }
      acc[mt][0] = __builtin_amdgcn_mfma_f32_16x16x32_bf16(af, bf0, acc[mt][0], 0, 0, 0);
      acc[mt][1] = __builtin_amdgcn_mfma_f32_16x16x32_bf16(af, bf1, acc[mt][1], 0, 0, 0);
    }
  }
#pragma unroll
  for (int kc = 1; kc < 13; ++kc) {
    int p = 2 * kc - 1 + (lg >> 1);
    float mu0 = (lg & 1) ? MU8 : 2.0f;
    s8v bf0 = *reinterpret_cast<const s8v*>(&wtf[(size_t)(kc * 4 + lg) * 1024 + col0 * 8]);
    s8v bf1 = *reinterpret_cast<const s8v*>(&wtf[(size_t)(kc * 4 + lg) * 1024 + col1 * 8]);
#pragma unroll
    for (int mt = 0; mt < 3; ++mt) {
      s8v af = rbf8(D_lds[mt * 16 + lr][p], mu0);
      acc[mt][0] = __builtin_amdgcn_mfma_f32_16x16x32_bf16(af, bf0, acc[mt][0], 0, 0, 0);
      acc[mt][1] = __builtin_amdgcn_mfma_f32_16x16x32_bf16(af, bf1, acc[mt][1], 0, 0, 0);
    }
  }

  // epilogue: direct stores (64B-coalesced per 16-lane group)
  float bias0 = bedge[col0], bias1 = bedge[col1];
  float* orow = Eout + (size_t)row * KTOP * EF;
#pragma unroll
  for (int mt = 0; mt < 3; ++mt) {
#pragma unroll
    for (int qq = 0; qq < 4; ++qq) {
      int m = mt * 16 + lg * 4 + qq;
      orow[m * EF + col0] = acc[mt][0][qq] + bias0;
      orow[m * EF + col1] = acc[mt][1][qq] + bias1;
    }
  }
}

extern "C" void kernel_launch(void* const* d_in, const int* in_sizes, int n_in,
                              void* d_out, int out_size, void* d_ws, size_t ws_size,
                              hipStream_t stream) {
  const float* X = (const float*)d_in[0];
  const float* mask = (const float*)d_in[1];
  const int* Ridx = (const int*)d_in[2];
  const int* chains = (const int*)d_in[3];
  const float* Wpos = (const float*)d_in[4];
  const float* bpos = (const float*)d_in[5];
  const float* Wedge = (const float*)d_in[6];
  const float* bedge = (const float*)d_in[7];

  float* Eout = (float*)d_out;
  float* EidxF = Eout + (size_t)BN * KTOP * EF;

  u16* wtf = (u16*)d_ws;                                   // 53248 u16
  float* atoms5p = (float*)((char*)d_ws + 53248 * 2);      // BN*20 f32
  float* capack4 = atoms5p + (size_t)BN * 20;              // BN*4 f32
  float* dtop = capack4 + (size_t)BN * 4;                  // BN*48 f32

  prep_kernel<<<(EIN * EF + BN + 255) / 256, 256, 0, stream>>>(X, Wedge, atoms5p, capack4, wtf);
  topk_kernel<<<BN, 256, 0, stream>>>(capack4, mask, dtop, EidxF);
  edge_kernel<<<BN, 256, 0, stream>>>(atoms5p, wtf, EidxF, dtop, Ridx, chains, Wpos, bpos, bedge, Eout);
}

// Round 5
// 92.715 us; speedup vs baseline: 1.1236x; 1.1236x over previous
//
#include <hip/hip_runtime.h>
#include <hip/hip_bf16.h>
#include <stdint.h>

#define BB   2
#define NN   2048
#define BN   (BB*NN)
#define KTOP 48
#define EIN  416
#define EF   128

typedef __attribute__((ext_vector_type(8))) short s8v;
typedef __attribute__((ext_vector_type(4))) float f32x4;
typedef __attribute__((ext_vector_type(4))) unsigned int u32x4;
typedef unsigned short u16;
typedef unsigned int u32;
typedef unsigned long long u64;

__device__ __constant__ int cPA[25] = {1,0,2,3,4,1,1,1,1,0,0,0,4,4,3,0,2,3,4,2,3,4,2,3,2};
__device__ __constant__ int cPB[25] = {1,0,2,3,4,0,2,3,4,2,3,4,2,3,2,1,1,1,1,0,0,0,4,4,3};

__device__ __forceinline__ u16 bf16u(float x) {
  __hip_bfloat16 h = __float2bfloat16(x);
  return *reinterpret_cast<u16*>(&h);
}
__device__ __forceinline__ u32 pack2(float lo, float hi) {
  return (u32)bf16u(lo) | ((u32)bf16u(hi) << 16);
}
// hardware packed f32->bf16 (RNE), 1 instr for 2 values
__device__ __forceinline__ u32 cvtpk(float lo, float hi) {
  u32 r;
  asm("v_cvt_pk_bf16_f32 %0, %1, %2" : "=v"(r) : "v"(lo), "v"(hi));
  return r;
}

// ---------------- prep: padded atoms [BN][5][4], Ca pack [BN][4], W_edge MFMA-tiled bf16 ----
__global__ __launch_bounds__(256) void prep_kernel(const float* __restrict__ X,
                                                   const float* __restrict__ W_edge,
                                                   float* __restrict__ atoms5p,
                                                   float* __restrict__ capack4,
                                                   u16* __restrict__ wtf) {
  int tid = blockIdx.x * 256 + threadIdx.x;
  if (tid < EIN * EF) {
    int k = tid >> 7, n = tid & 127;
    wtf[((size_t)(k >> 3)) * 1024 + n * 8 + (k & 7)] = bf16u(W_edge[tid]);
  } else if (tid < EIN * EF + BN) {
    int idx = tid - EIN * EF;
    const float* x = X + (size_t)idx * 12;
    float Nx = x[0], Ny = x[1], Nz = x[2];
    float Cax = x[3], Cay = x[4], Caz = x[5];
    float Cx = x[6], Cy = x[7], Cz = x[8];
    float Ox = x[9], Oy = x[10], Oz = x[11];
    float bx = Cax - Nx, by = Cay - Ny, bz = Caz - Nz;
    float cx = Cx - Cax, cy = Cy - Cay, cz = Cz - Caz;
    float ax = by * cz - bz * cy;
    float ay = bz * cx - bx * cz;
    float az = bx * cy - by * cx;
    float Cbx = -0.58273431f * ax + 0.56802827f * bx - 0.54067466f * cx + Cax;
    float Cby = -0.58273431f * ay + 0.56802827f * by - 0.54067466f * cy + Cay;
    float Cbz = -0.58273431f * az + 0.56802827f * bz - 0.54067466f * cz + Caz;
    f32x4* o = (f32x4*)(atoms5p + (size_t)idx * 20);
    o[0] = (f32x4){Nx, Ny, Nz, 0.f};
    o[1] = (f32x4){Cax, Cay, Caz, 0.f};
    o[2] = (f32x4){Cx, Cy, Cz, 0.f};
    o[3] = (f32x4){Ox, Oy, Oz, 0.f};
    o[4] = (f32x4){Cbx, Cby, Cbz, 0.f};
    *(f32x4*)(capack4 + (size_t)idx * 4) = (f32x4){Cax, Cay, Caz, 0.f};
  }
}

// exclusive block scan over 256 threads
__device__ __forceinline__ u32 blockExclScan(u32 v, u32* scanw, int t) {
  int lane = t & 63, w = t >> 6;
  u32 inc = v;
#pragma unroll
  for (int off = 1; off < 64; off <<= 1) {
    u32 o = __shfl_up(inc, off);
    if (lane >= off) inc += o;
  }
  if (lane == 63) scanw[w] = inc;
  __syncthreads();
  u32 base = 0;
  for (int ww = 0; ww < w; ++ww) base += scanw[ww];
  __syncthreads();
  return base + inc - v;
}

template<int NB, bool CHKPREF>
__device__ __forceinline__ void radix_round(u32* hist, u32* scanw, u32* selinfo, int t,
                                            const u32* kv, u32 pref, int prefShift,
                                            int binShift, u32 binMask, u32 r) {
  const int PB = NB / 256;
#pragma unroll
  for (int q = 0; q < PB / 4; ++q)
    *(u32x4*)&hist[t * PB + q * 4] = (u32x4){0, 0, 0, 0};
  __syncthreads();
#pragma unroll
  for (int s = 0; s < 8; ++s) {
    bool ok = (!CHKPREF) || ((kv[s] >> prefShift) == pref);
    if (ok) atomicAdd(&hist[(kv[s] >> binShift) & binMask], 1u);
  }
  __syncthreads();
  u32 loc[PB];
  u32 sum = 0;
#pragma unroll
  for (int q = 0; q < PB / 4; ++q) {
    u32x4 lv = *(u32x4*)&hist[t * PB + q * 4];
    loc[q * 4 + 0] = lv.x; loc[q * 4 + 1] = lv.y;
    loc[q * 4 + 2] = lv.z; loc[q * 4 + 3] = lv.w;
    sum += lv.x + lv.y + lv.z + lv.w;
  }
  int lane = t & 63, w = t >> 6;
  u32 inc = sum;
#pragma unroll
  for (int off = 1; off < 64; off <<= 1) {
    u32 o = __shfl_up(inc, off);
    if (lane >= off) inc += o;
  }
  if (lane == 63) scanw[w] = inc;
  __syncthreads();
  u32 base = 0;
  for (int ww = 0; ww < w; ++ww) base += scanw[ww];
  u32 c = base + inc - sum;
#pragma unroll
  for (int q = 0; q < PB; ++q) {
    u32 nc = c + loc[q];
    if (c < r && r <= nc) { selinfo[0] = (u32)(t * PB + q); selinfo[1] = r - c; }
    c = nc;
  }
  __syncthreads();
}

// ---------------- top-48 per row: exact radix select ----------------
__global__ __launch_bounds__(256) void topk_kernel(const float* __restrict__ capack4,
                                                   const float* __restrict__ mask,
                                                   float* __restrict__ dtop,
                                                   float* __restrict__ eidx_f) {
  __shared__ u32 hist[4096];
  __shared__ u32 scanw[4];
  __shared__ u32 selinfo[2];
  __shared__ float redf[4];
  __shared__ u64 win[64];

  int row = blockIdx.x;
  int b = row >> 11, i = row & (NN - 1);
  int t = threadIdx.x, lane = t & 63, w = t >> 6;
  const float* cab4 = capack4 + (size_t)b * NN * 4;
  const float* mrow = mask + (size_t)b * NN;
  f32x4 ci = *(const f32x4*)&cab4[(size_t)i * 4];
  float mi = mrow[i];
  f32x4 mk0 = *(const f32x4*)&mrow[t * 8];
  f32x4 mk1 = *(const f32x4*)&mrow[t * 8 + 4];

  float dvv[8], m2v[8];
  float lmax = 0.f;
#pragma unroll
  for (int s = 0; s < 8; ++s) {
    f32x4 cj = *(const f32x4*)&cab4[(size_t)(t * 8 + s) * 4];
    float dx = ci.x - cj.x, dy = ci.y - cj.y, dz = ci.z - cj.z;
    float d = sqrtf(dx * dx + dy * dy + dz * dz + 1e-6f);
    float mj = (s < 4) ? mk0[s] : mk1[s - 4];
    float m2 = mi * mj;
    float D = m2 * d;
    dvv[s] = D; m2v[s] = m2;
    lmax = fmaxf(lmax, D);
  }
#pragma unroll
  for (int off = 32; off >= 1; off >>= 1) lmax = fmaxf(lmax, __shfl_xor(lmax, off));
  if (lane == 0) redf[w] = lmax;
  __syncthreads();
  float rmax = fmaxf(fmaxf(redf[0], redf[1]), fmaxf(redf[2], redf[3]));

  u32 kv[8];
#pragma unroll
  for (int s = 0; s < 8; ++s)
    kv[s] = __float_as_uint(dvv[s] + (1.0f - m2v[s]) * rmax);

  u32 r = KTOP;
  radix_round<4096, false>(hist, scanw, selinfo, t, kv, 0, 0, 20, 0xFFFu, r);
  u32 sel1 = selinfo[0]; r = selinfo[1];
  radix_round<1024, true>(hist, scanw, selinfo, t, kv, sel1, 20, 10, 0x3FFu, r);
  u32 sel2 = selinfo[0]; r = selinfo[1];
  u32 pref12 = (sel1 << 10) | sel2;
  radix_round<1024, true>(hist, scanw, selinfo, t, kv, pref12, 10, 0, 0x3FFu, r);
  u32 sel3 = selinfo[0];
  u32 takeEq = selinfo[1];
  u32 T = (sel1 << 20) | (sel2 << 10) | sel3;

  u32 lcnt = 0, ecnt = 0;
#pragma unroll
  for (int s = 0; s < 8; ++s) { lcnt += (kv[s] < T); ecnt += (kv[s] == T); }
  u32 ebase = blockExclScan(ecnt, scanw, t);
  u32 taken = 0;
  if (ebase < takeEq) { u32 room = takeEq - ebase; taken = room < ecnt ? room : ecnt; }
  u32 wbase = blockExclScan(lcnt + taken, scanw, t);
  u32 slot = wbase, tleft = taken;
#pragma unroll
  for (int s = 0; s < 8; ++s) {
    u32 j = (u32)(t * 8 + s);
    if (kv[s] < T) {
      win[slot++] = ((u64)kv[s] << 32) | j;
    } else if (kv[s] == T && tleft) {
      win[slot++] = ((u64)kv[s] << 32) | j;
      tleft--;
    }
  }
  __syncthreads();

  if (w == 0) {
    u64 key = (lane < KTOP) ? win[lane] : ~0ull;
#pragma unroll
    for (int k = 2; k <= 64; k <<= 1) {
#pragma unroll
      for (int jj = k >> 1; jj >= 1; jj >>= 1) {
        u64 p = __shfl_xor(key, jj);
        bool lowerl = (lane & jj) == 0;
        bool asc = (lane & k) == 0;
        u64 mn = p < key ? p : key;
        u64 mx = p < key ? key : p;
        key = (lowerl == asc) ? mn : mx;
      }
    }
    if (lane < KTOP) {
      u32 j = (u32)(key & 0xffffffffu);
      eidx_f[row * KTOP + lane] = (float)j;
      dtop[row * KTOP + lane] = __uint_as_float((u32)(key >> 32));
    }
  }
}

// RBF 8-vector via geometric recurrence + hw packed bf16 convert (~25 VALU ops)
__device__ __forceinline__ s8v rbf8(float D, float mu0) {
  float Dc = fminf(D, 40.0f);
  float t0 = (Dc - mu0) * 0.8f;
  float v0 = __expf(-t0 * t0);
  float g = __expf(fmaf(2.13333333f, t0, -1.13777778f));
  const float C = 0.10273985f;
  float v1 = v0 * g; g *= C;
  float v2 = v1 * g; g *= C;
  float v3 = v2 * g; g *= C;
  float v4 = v3 * g; g *= C;
  float v5 = v4 * g; g *= C;
  float v6 = v5 * g; g *= C;
  float v7 = v6 * g;
  union { u32x4 u; s8v s; } cv;
  cv.u = (u32x4){cvtpk(v0, v1), cvtpk(v2, v3), cvtpk(v4, v5), cvtpk(v6, v7)};
  return cv.s;
}

// ---------------- edge: one wave per residue, zero barriers ----------------
// Wave computes its 48x25 distance matrix + pos block into private LDS, then the
// full 48x416 @ 416x128 GEMM with A-fragments generated in-register (each exactly once).
__global__ __launch_bounds__(64) void edge_kernel(const float* __restrict__ atoms5p,
                                                  const u16* __restrict__ wtf,
                                                  const float* __restrict__ eidx_f,
                                                  const float* __restrict__ dtop,
                                                  const int* __restrict__ Ridx,
                                                  const int* __restrict__ chains,
                                                  const float* __restrict__ Wpos,
                                                  const float* __restrict__ bpos,
                                                  const float* __restrict__ bedge,
                                                  float* __restrict__ Eout) {
  __shared__ float D_lds[KTOP][26];   // p=0: dtop; p=1..24 pair dists; pad 26 -> conflict-free
  __shared__ u32 pos_lds[KTOP][8];    // positional cols 0..15, packed bf16
  __shared__ int jbuf[KTOP];
  __shared__ f32x4 aI_lds[5];

  int lane = threadIdx.x;
  int row = blockIdx.x;
  int b = row >> 11, i = row & (NN - 1);
  const float* atomsB = atoms5p + (size_t)b * NN * 20;

  if (lane < 5) aI_lds[lane] = *(const f32x4*)&atomsB[(size_t)i * 20 + lane * 4];
  if (lane < KTOP) {
    int j = (int)eidx_f[(size_t)row * KTOP + lane];
    jbuf[lane] = j;
    D_lds[lane][0] = dtop[(size_t)row * KTOP + lane];
    int Ri = Ridx[b * NN + i], Rj = Ridx[b * NN + j];
    int same = (chains[b * NN + i] == chains[b * NN + j]);
    int off = Ri - Rj + 32;
    off = off < 0 ? 0 : (off > 64 ? 64 : off);
    int drow = same ? off : 65;
    const float* wr = Wpos + drow * 16;
    u32 pk[8];
#pragma unroll
    for (int h = 0; h < 4; ++h) {
      f32x4 wv = *(const f32x4*)&wr[h * 4];
      f32x4 bv = *(const f32x4*)&bpos[h * 4];
      pk[h * 2 + 0] = cvtpk(wv.x + bv.x, wv.y + bv.y);
      pk[h * 2 + 1] = cvtpk(wv.z + bv.z, wv.w + bv.w);
    }
    *(u32x4*)&pos_lds[lane][0] = (u32x4){pk[0], pk[1], pk[2], pk[3]};
    *(u32x4*)&pos_lds[lane][4] = (u32x4){pk[4], pk[5], pk[6], pk[7]};
  }

  // 1152 pair distances, 18 per lane (wave-private LDS: ordering via lgkmcnt, no barrier)
#pragma unroll
  for (int q = 0; q < 18; ++q) {
    int e = q * 64 + lane;
    int k = e / 24;
    int p = e - k * 24 + 1;
    int j = jbuf[k];
    f32x4 I = aI_lds[cPA[p]];
    f32x4 J = *(const f32x4*)&atomsB[(size_t)j * 20 + cPB[p] * 4];
    float dx = I.x - J.x, dy = I.y - J.y, dz = I.z - J.z;
    D_lds[k][p] = __builtin_amdgcn_sqrtf(dx * dx + dy * dy + dz * dz + 1e-6f);
  }

  // GEMM: C(48x128) = A(48x416) B(416x128); 3 m-tiles x 8 n-tiles x 13 k-steps
  int lr = lane & 15, lg = lane >> 4;
  const u16* wk = wtf + (size_t)lg * 1024 + lr * 8;
  const float MU8 = 12.6666667f;
  f32x4 acc[3][8] = {};

  {  // kc = 0: cols 0..15 positional, 16..31 RBF p=0
    s8v a0, a1, a2;
    if (lg < 2) {
      a0 = *reinterpret_cast<const s8v*>(&pos_lds[lr][lg * 4]);
      a1 = *reinterpret_cast<const s8v*>(&pos_lds[16 + lr][lg * 4]);
      a2 = *reinterpret_cast<const s8v*>(&pos_lds[32 + lr][lg * 4]);
    } else {
      float mu0 = (lg == 2) ? 2.0f : MU8;
      a0 = rbf8(D_lds[lr][0], mu0);
      a1 = rbf8(D_lds[16 + lr][0], mu0);
      a2 = rbf8(D_lds[32 + lr][0], mu0);
    }
#pragma unroll
    for (int nt = 0; nt < 8; ++nt) {
      s8v bv = *reinterpret_cast<const s8v*>(wk + nt * 128);
      acc[0][nt] = __builtin_amdgcn_mfma_f32_16x16x32_bf16(a0, bv, acc[0][nt], 0, 0, 0);
      acc[1][nt] = __builtin_amdgcn_mfma_f32_16x16x32_bf16(a1, bv, acc[1][nt], 0, 0, 0);
      acc[2][nt] = __builtin_amdgcn_mfma_f32_16x16x32_bf16(a2, bv, acc[2][nt], 0, 0, 0);
    }
  }
#pragma unroll
  for (int kc = 1; kc < 13; ++kc) {
    int p = 2 * kc - 1 + (lg >> 1);
    float mu0 = (lg & 1) ? MU8 : 2.0f;
    s8v a0 = rbf8(D_lds[lr][p], mu0);
    s8v a1 = rbf8(D_lds[16 + lr][p], mu0);
    s8v a2 = rbf8(D_lds[32 + lr][p], mu0);
    const u16* wkc = wk + (size_t)kc * 4096;
#pragma unroll
    for (int nt = 0; nt < 8; ++nt) {
      s8v bv = *reinterpret_cast<const s8v*>(wkc + nt * 128);
      acc[0][nt] = __builtin_amdgcn_mfma_f32_16x16x32_bf16(a0, bv, acc[0][nt], 0, 0, 0);
      acc[1][nt] = __builtin_amdgcn_mfma_f32_16x16x32_bf16(a1, bv, acc[1][nt], 0, 0, 0);
      acc[2][nt] = __builtin_amdgcn_mfma_f32_16x16x32_bf16(a2, bv, acc[2][nt], 0, 0, 0);
    }
  }

  // epilogue: bias + direct stores (16-lane groups write 64B contiguous)
  float bias[8];
#pragma unroll
  for (int nt = 0; nt < 8; ++nt) bias[nt] = bedge[nt * 16 + lr];
  float* orow = Eout + (size_t)row * KTOP * EF;
#pragma unroll
  for (int mt = 0; mt < 3; ++mt) {
#pragma unroll
    for (int qq = 0; qq < 4; ++qq) {
      float* pr = orow + (size_t)(mt * 16 + lg * 4 + qq) * EF + lr;
#pragma unroll
      for (int nt = 0; nt < 8; ++nt)
        pr[nt * 16] = acc[mt][nt][qq] + bias[nt];
    }
  }
}

extern "C" void kernel_launch(void* const* d_in, const int* in_sizes, int n_in,
                              void* d_out, int out_size, void* d_ws, size_t ws_size,
                              hipStream_t stream) {
  const float* X = (const float*)d_in[0];
  const float* mask = (const float*)d_in[1];
  const int* Ridx = (const int*)d_in[2];
  const int* chains = (const int*)d_in[3];
  const float* Wpos = (const float*)d_in[4];
  const float* bpos = (const float*)d_in[5];
  const float* Wedge = (const float*)d_in[6];
  const float* bedge = (const float*)d_in[7];

  float* Eout = (float*)d_out;
  float* EidxF = Eout + (size_t)BN * KTOP * EF;

  u16* wtf = (u16*)d_ws;                                   // 53248 u16
  float* atoms5p = (float*)((char*)d_ws + 53248 * 2);      // BN*20 f32
  float* capack4 = atoms5p + (size_t)BN * 20;              // BN*4 f32
  float* dtop = capack4 + (size_t)BN * 4;                  // BN*48 f32

  prep_kernel<<<(EIN * EF + BN + 255) / 256, 256, 0, stream>>>(X, Wedge, atoms5p, capack4, wtf);
  topk_kernel<<<BN, 256, 0, stream>>>(capack4, mask, dtop, EidxF);
  edge_kernel<<<BN, 64, 0, stream>>>(atoms5p, wtf, EidxF, dtop, Ridx, chains, Wpos, bpos, bedge, Eout);
}